// Round 1
// 1516.477 us; speedup vs baseline: 1.0121x; 1.0121x over previous
//
#include <hip/hip_runtime.h>
#include <cstddef>

#define B_ 2
#define T_ 4096
#define NQ_ 256
#define NAUX_ 28
#define NR_ 512
#define NS_ 256
#define L_ 30

typedef _Float16 half_t;
typedef __attribute__((ext_vector_type(8))) _Float16 f16x8;
typedef __attribute__((ext_vector_type(4))) _Float16 f16x4;
typedef __attribute__((ext_vector_type(4))) float f32x4;

__device__ inline half_t f2h(float f) { return (half_t)f; }
__device__ inline float h2f(half_t h) { return (float)h; }

// async global->LDS, 16 B per lane; LDS dest = wave base + lane*16
__device__ __forceinline__ void gload16(const void* g, void* l) {
    __builtin_amdgcn_global_load_lds(
        (const __attribute__((address_space(1))) unsigned int*)g,
        (__attribute__((address_space(3))) unsigned int*)l, 16, 0, 0);
}

// ---------------------------------------------------------------------------
// Weight fragment-blob layout: for M x K weights, blob(mg, ks) holds the
// 16-row x 32-col MFMA A-fragment for m in [mg*16,mg*16+16), k in [ks*32,+32):
// 64 lanes x 8 halves contiguous; lane l -> row mg*16+(l&15), k ks*32+(l>>4)*8.
// Flat half offset: (mg*NKS + ks)*512 + lane*8, NKS = K/32.
// ---------------------------------------------------------------------------

// ---------------------------------------------------------------------------
// Fused gates GEMM + gating. DUAL-TAP restructure: each K-iteration stages
// BOTH the cur-tap 64-k slice (LDS rows [0,128)) and the past-tap slice
// (rows [128,256)) into one double buffer, and computes 64 MFMA behind a
// single barrier. 9 iterations (8 dual + 1 aux) instead of 17 -> barrier
// drains halved. Virtual chunk v: [0,8)=cur, [8,16)=past(t-dil), 16=aux.
// grid (32, 8, B), 256 threads.
// ---------------------------------------------------------------------------
__global__ __launch_bounds__(256, 2) void gates_gemm(
    const half_t* __restrict__ actB, const half_t* __restrict__ Wf,
    const float* __restrict__ biasG, half_t* __restrict__ g,
    const half_t* __restrict__ zbuf, int dil)
{
    __shared__ __align__(16) half_t sB[2][256 * 64];   // 64 KB, 2 blocks/CU

    const int tid = threadIdx.x;
    const int b = blockIdx.z;
    const int tB = blockIdx.x * 128;
    const int w = tid >> 6, lane = tid & 63;
    const int wm = w >> 1, wn = w & 1;
    const int l15 = lane & 15, lg = lane >> 4;
    const int rr = lane >> 3, cc = lane & 7;
    const int sc8 = cc ^ rr;

    f32x4 acc[4][4] = {};
    f16x8 aC[8], aP[8];

    const int mgW = blockIdx.y * 8 + wm * 4;   // blob m-group base for this wave

    auto loadA = [&](f16x8* d, int v) {
#pragma unroll
        for (int i = 0; i < 4; i++)
#pragma unroll
            for (int s = 0; s < 2; s++)
                d[i * 2 + s] = *(const f16x8*)&Wf[((size_t)(mgW + i) * 34 + v * 2 + s) * 512 + lane * 8];
    };
    auto stageSlice = [&](int v, int rowbase, int buf) {
#pragma unroll
        for (int it = 0; it < 4; it++) {
            const int t = tB + w * 32 + it * 8 + rr;
            const half_t* p;
            if (v < 8) {
                p = actB + ((size_t)b * T_ + t) * 576 + v * 64;
            } else if (v < 16) {
                const int tp = t - dil;
                p = (tp >= 0) ? actB + ((size_t)b * T_ + tp) * 576 + (v - 8) * 64
                              : zbuf;
            } else {
                p = actB + ((size_t)b * T_ + t) * 576 + 512;
            }
            gload16(p + sc8 * 8, &sB[buf][(rowbase + w * 32 + it * 8) * 64]);
        }
    };
    auto compute = [&](const f16x8* a, int rowbase, int buf) {
#pragma unroll
        for (int s = 0; s < 2; s++) {
            f16x8 bv[4];
#pragma unroll
            for (int j = 0; j < 4; j++) {
                const int r = rowbase + wn * 64 + j * 16 + l15;
                bv[j] = *(const f16x8*)&sB[buf][r * 64 + (((s * 4 + lg) ^ (l15 & 7)) * 8)];
            }
#pragma unroll
            for (int i = 0; i < 4; i++)
#pragma unroll
                for (int j = 0; j < 4; j++)
                    acc[i][j] = __builtin_amdgcn_mfma_f32_16x16x32_f16(a[i * 2 + s], bv[j], acc[i][j], 0, 0, 0);
        }
    };

    // prologue: stage dual chunk 0, prefetch A for cur0/past0
    stageSlice(0, 0, 0);
    stageSlice(8, 128, 0);
    loadA(aC, 0);
    loadA(aP, 8);
#pragma unroll
    for (int kc = 0; kc < 9; kc++) {
        __syncthreads();               // drains stage(kc) + in-flight A loads
        const int nb = (kc + 1) & 1;
        if (kc < 7) {
            stageSlice(kc + 1, 0, nb);
            stageSlice(kc + 9, 128, nb);
        } else if (kc == 7) {
            stageSlice(16, 0, nb);     // next iter = aux chunk
        }
        if (kc < 8) {
            compute(aC, 0, kc & 1);                    // cur tap (32 MFMA)
            loadA(aC, (kc < 7) ? (kc + 1) : 16);       // aC free -> prefetch
            compute(aP, 128, kc & 1);                  // past tap (32 MFMA)
            if (kc < 7) loadA(aP, kc + 9);             // aP free -> prefetch
        } else {
            compute(aC, 0, kc & 1);                    // aux (32 MFMA)
        }
    }

    const int gidx = blockIdx.y * 2 + wm;
    const int t0 = tB + wn * 64 + l15;
#pragma unroll
    for (int i = 0; i < 2; i++) {
        const int c = gidx * 32 + i * 16 + lg * 4;
        const float4 bs = *(const float4*)&biasG[gidx * 64 + i * 16 + lg * 4];
        const float4 bt4 = *(const float4*)&biasG[gidx * 64 + 32 + i * 16 + lg * 4];
        const float bsa[4] = {bs.x, bs.y, bs.z, bs.w};
        const float bta[4] = {bt4.x, bt4.y, bt4.z, bt4.w};
#pragma unroll
        for (int j = 0; j < 4; j++) {
            const int t = t0 + j * 16;
            f16x4 o;
#pragma unroll
            for (int e = 0; e < 4; e++) {
                const float sv = acc[i][j][e] + bsa[e];
                const float tv = acc[i + 2][j][e] + bta[e];
                const float sg = 1.f / (1.f + __expf(-sv));
                const float ex = __expf(-2.f * tv);
                const float th = (1.f - ex) / (1.f + ex);
                o[e] = f2h(sg * th);
            }
            *(f16x4*)(g + ((size_t)b * T_ + t) * 512 + c) = o;
        }
    }
}

// ---------------------------------------------------------------------------
// Generic GEMM, BK=128 per barrier: each iteration stages two 64-k sub-slices
// (v=2kc -> LDS rows [0,128), v=2kc+1 -> rows [128,256)) and computes 64 MFMA
// behind one barrier. NITER = K/128 (4 or 2). EPI: 0 fp16, 1 fp16+relu,
// 2 f32, 3 fused res/skip fp16 RMW (m<512 actB, m>=512 skipH).
// ---------------------------------------------------------------------------
template<int K, int EPI>
__global__ __launch_bounds__(256, 2) void gemm_mfma(
    const half_t* __restrict__ X, const half_t* __restrict__ Wf,
    const float* __restrict__ bias, void* __restrict__ out, int M,
    half_t* __restrict__ actB, half_t* __restrict__ skipH)
{
    constexpr int NITER = K / 128;
    constexpr int NKS = K / 32;
    __shared__ __align__(16) half_t sB[2][256 * 64];   // 64 KB

    const int tid = threadIdx.x;
    const int b = blockIdx.z;
    const int tB = blockIdx.x * 128;
    const int mB = blockIdx.y * 128;
    const int w = tid >> 6, lane = tid & 63;
    const int wm = w >> 1, wn = w & 1;
    const int l15 = lane & 15, lg = lane >> 4;
    const int rr = lane >> 3, cc = lane & 7;
    const int sc8 = cc ^ rr;

    f32x4 acc[4][4] = {};
    f16x8 aC[8], aP[8];

    const int mgW = (mB >> 4) + wm * 4;
    const half_t* Xb = X + ((size_t)b * T_ + tB) * K;

    auto loadA = [&](f16x8* d, int v) {
#pragma unroll
        for (int i = 0; i < 4; i++)
#pragma unroll
            for (int s = 0; s < 2; s++)
                d[i * 2 + s] = *(const f16x8*)&Wf[((size_t)(mgW + i) * NKS + v * 2 + s) * 512 + lane * 8];
    };
    auto stageSlice = [&](int v, int rowbase, int buf) {
#pragma unroll
        for (int it = 0; it < 4; it++) {
            const int row = w * 32 + it * 8;
            gload16(Xb + (size_t)(row + rr) * K + v * 64 + sc8 * 8,
                    &sB[buf][(rowbase + row) * 64]);
        }
    };
    auto compute = [&](const f16x8* a, int rowbase, int buf) {
#pragma unroll
        for (int s = 0; s < 2; s++) {
            f16x8 bv[4];
#pragma unroll
            for (int j = 0; j < 4; j++) {
                const int r = rowbase + wn * 64 + j * 16 + l15;
                bv[j] = *(const f16x8*)&sB[buf][r * 64 + (((s * 4 + lg) ^ (l15 & 7)) * 8)];
            }
#pragma unroll
            for (int i = 0; i < 4; i++)
#pragma unroll
                for (int j = 0; j < 4; j++)
                    acc[i][j] = __builtin_amdgcn_mfma_f32_16x16x32_f16(a[i * 2 + s], bv[j], acc[i][j], 0, 0, 0);
        }
    };

    stageSlice(0, 0, 0);
    stageSlice(1, 128, 0);
    loadA(aC, 0);
    loadA(aP, 1);
#pragma unroll
    for (int kc = 0; kc < NITER; kc++) {
        __syncthreads();
        if (kc + 1 < NITER) {
            stageSlice(2 * kc + 2, 0, (kc + 1) & 1);
            stageSlice(2 * kc + 3, 128, (kc + 1) & 1);
        }
        compute(aC, 0, kc & 1);
        if (kc + 1 < NITER) loadA(aC, 2 * kc + 2);
        compute(aP, 128, kc & 1);
        if (kc + 1 < NITER) loadA(aP, 2 * kc + 3);
    }

    const int n0 = tB + wn * 64 + l15;
#pragma unroll
    for (int i = 0; i < 4; i++) {
        const int m = mB + wm * 64 + i * 16 + lg * 4;
        float4 bv = make_float4(0.f, 0.f, 0.f, 0.f);
        if (bias) bv = *(const float4*)&bias[m];
#pragma unroll
        for (int j = 0; j < 4; j++) {
            const int t = n0 + j * 16;
            float o0 = acc[i][j][0] + bv.x, o1 = acc[i][j][1] + bv.y;
            float o2 = acc[i][j][2] + bv.z, o3 = acc[i][j][3] + bv.w;
            if (EPI == 1) {
                o0 = fmaxf(o0, 0.f); o1 = fmaxf(o1, 0.f);
                o2 = fmaxf(o2, 0.f); o3 = fmaxf(o3, 0.f);
            }
            if (EPI == 3) {
                const size_t bt = (size_t)b * T_ + t;
                half_t* p = (mB < 512) ? (actB + bt * 576 + m)
                                       : (skipH + bt * 256 + (m - 512));
                f16x4 old = *(const f16x4*)p;
                f16x4 nv = {f2h(h2f(old.x) + o0), f2h(h2f(old.y) + o1),
                            f2h(h2f(old.z) + o2), f2h(h2f(old.w) + o3)};
                *(f16x4*)p = nv;
            } else {
                const size_t off = ((size_t)b * T_ + t) * M + m;
                if (EPI == 2) {
                    *(float4*)((float*)out + off) = make_float4(o0, o1, o2, o3);
                } else {
                    f16x4 ov = {f2h(o0), f2h(o1), f2h(o2), f2h(o3)};
                    *(f16x4*)((half_t*)out + off) = ov;
                }
            }
        }
    }
}

// relu(skipH) -> fp16 dense
__global__ __launch_bounds__(256) void relupack_kernel(
    const half_t* __restrict__ skipH, half_t* __restrict__ outp)
{
    const int idx = blockIdx.x * 256 + threadIdx.x;     // 8192*64
    const int c = (idx & 63) * 4;
    const int bt = idx >> 6;
    const f16x4 v = *(const f16x4*)(skipH + (size_t)bt * 256 + c);
    f16x4 o = {f2h(fmaxf(h2f(v.x), 0.f)), f2h(fmaxf(h2f(v.y), 0.f)),
               f2h(fmaxf(h2f(v.z), 0.f)), f2h(fmaxf(h2f(v.w), 0.f))};
    *(f16x4*)(outp + (size_t)bt * 256 + c) = o;
}

// ---------------------------------------------------------------------------
// Embed: actB[t][c] = fp16(cw[c][x[t]][1] + cw[c][x[t-1]][0] + cb[c])
// ---------------------------------------------------------------------------
__global__ __launch_bounds__(256) void embed_kernel(
    const int* __restrict__ x, const float* __restrict__ cw,
    const float* __restrict__ cb, half_t* __restrict__ actB)
{
    const int t = blockIdx.x, b = blockIdx.y;
    const int idc = x[b * T_ + t];
    const int idp = (t > 0) ? x[b * T_ + t - 1] : -1;
    const size_t bt = (size_t)b * T_ + t;
    for (int c = threadIdx.x; c < 512; c += 256) {
        float v = cw[(c * 256 + idc) * 2 + 1] + cb[c];
        if (idp >= 0) v += cw[(c * 256 + idp) * 2 + 0];
        actB[bt * 576 + c] = f2h(v);
    }
}

// aux channels: actB[t][512+j] = fp16(h[b][j][t]) for j<28 else 0
__global__ __launch_bounds__(256) void packh_kernel(
    const float* __restrict__ h, half_t* __restrict__ actB)
{
    const int idx = blockIdx.x * 256 + threadIdx.x;     // 8192*64
    const int j = idx & 63;
    const int bt = idx >> 6;
    const int b = bt >> 12, t = bt & 4095;
    const float v = (j < 28) ? h[((size_t)b * NAUX_ + j) * T_ + t] : 0.f;
    actB[(size_t)bt * 576 + 512 + j] = f2h(v);
}

// ---------------------------------------------------------------------------
// Pack gate weights into blob layout. Wg per layer = 64 mg x 34 ks x 512 h.
// Thread -> (l, mg, ks<16, lane): reads 16 floats (8 k x 2 taps), writes
// cur blob slot (ks) and past blob slot (16+ks), 16 B per store,
// wave-contiguous 1 KB.
// ---------------------------------------------------------------------------
__global__ __launch_bounds__(256) void packgate_kernel(
    const float* __restrict__ dsw, const float* __restrict__ dtw,
    half_t* __restrict__ Wg)
{
    const int idx = blockIdx.x * 256 + threadIdx.x;     // 30*64*16*64
    const int lane = idx & 63;
    const int ks = (idx >> 6) & 15;
    const int mg = (idx >> 10) & 63;
    const int l = idx >> 16;
    const int r = mg * 16 + (lane & 15);
    const int rsub = r & 63;
    const int c = (r >> 6) * 32 + (rsub & 31);
    const float* src = (rsub < 32) ? dsw : dtw;
    const size_t base = ((size_t)(l * 512 + c) * 512 + ks * 32 + (lane >> 4) * 8) * 2;
    const float4* p = (const float4*)(src + base);
    const float4 q0 = p[0], q1 = p[1], q2 = p[2], q3 = p[3];
    f16x8 cur = {f2h(q0.y), f2h(q0.w), f2h(q1.y), f2h(q1.w),
                 f2h(q2.y), f2h(q2.w), f2h(q3.y), f2h(q3.w)};
    f16x8 pst = {f2h(q0.x), f2h(q0.z), f2h(q1.x), f2h(q1.z),
                 f2h(q2.x), f2h(q2.z), f2h(q3.x), f2h(q3.z)};
    half_t* dst = Wg + (size_t)l * 1114112;
    *(f16x8*)&dst[((size_t)(mg * 34 + ks) * 64 + lane) * 8] = cur;
    *(f16x8*)&dst[((size_t)(mg * 34 + 16 + ks) * 64 + lane) * 8] = pst;
}

// aux blob slots ks=32,33 of Wg
__global__ __launch_bounds__(256) void packgaux_kernel(
    const float* __restrict__ asw, const float* __restrict__ atw,
    half_t* __restrict__ Wg)
{
    const int idx = blockIdx.x * 256 + threadIdx.x;     // 30*64*2*64
    const int lane = idx & 63;
    const int ksd = (idx >> 6) & 1;
    const int mg = (idx >> 7) & 63;
    const int l = idx >> 13;
    const int r = mg * 16 + (lane & 15);
    const int rsub = r & 63;
    const int c = (r >> 6) * 32 + (rsub & 31);
    const float* src = (rsub < 32) ? asw : atw;
    const int j0 = ksd * 32 + (lane >> 4) * 8;
    f16x8 v = {};
#pragma unroll
    for (int e = 0; e < 8; e++) {
        const int j = j0 + e;
        if (j < NAUX_) v[e] = f2h(src[(size_t)(l * 512 + c) * NAUX_ + j]);
    }
    Wg += (size_t)l * 1114112;
    *(f16x8*)&Wg[((size_t)(mg * 34 + 32 + ksd) * 64 + lane) * 8] = v;
}

// sr weights blob: 48 mg x 16 ks x 512 h per layer
__global__ __launch_bounds__(256) void packsr_kernel(
    const float* __restrict__ rsw, const float* __restrict__ skw,
    half_t* __restrict__ Wsr)
{
    const int idx = blockIdx.x * 256 + threadIdx.x;     // 30*48*16*64
    const int lane = idx & 63;
    const int ks = (idx >> 6) & 15;
    const int mg = (idx >> 10) % 48;
    const int l = (idx >> 10) / 48;
    const int r = mg * 16 + (lane & 15);
    const int kb = ks * 32 + (lane >> 4) * 8;
    const float* src = (r < 512) ? (rsw + ((size_t)l * 512 + r) * 512 + kb)
                                 : (skw + ((size_t)l * 256 + (r - 512)) * 512 + kb);
    const float4 q0 = ((const float4*)src)[0], q1 = ((const float4*)src)[1];
    f16x8 v = {f2h(q0.x), f2h(q0.y), f2h(q0.z), f2h(q0.w),
               f2h(q1.x), f2h(q1.y), f2h(q1.z), f2h(q1.w)};
    *(f16x8*)&Wsr[(size_t)l * 393216 + ((size_t)(mg * 16 + ks) * 64 + lane) * 8] = v;
}

// post weights blob: 16 mg x 8 ks x 512 h per matrix
__global__ __launch_bounds__(256) void packpost_kernel(
    const float* __restrict__ p1w, const float* __restrict__ p2w,
    const float* __restrict__ lw, half_t* __restrict__ Wpost)
{
    const int idx = blockIdx.x * 256 + threadIdx.x;     // 3*16*8*64
    const int lane = idx & 63;
    const int ks = (idx >> 6) & 7;
    const int mg = (idx >> 9) & 15;
    const int mi = idx >> 13;
    const float* src = (mi == 0) ? p1w : (mi == 1) ? p2w : lw;
    const int r = mg * 16 + (lane & 15);
    const int kb = ks * 32 + (lane >> 4) * 8;
    const float4 q0 = ((const float4*)(src + (size_t)r * 256 + kb))[0];
    const float4 q1 = ((const float4*)(src + (size_t)r * 256 + kb))[1];
    f16x8 v = {f2h(q0.x), f2h(q0.y), f2h(q0.z), f2h(q0.w),
               f2h(q1.x), f2h(q1.y), f2h(q1.z), f2h(q1.w)};
    *(f16x8*)&Wpost[(size_t)mi * 65536 + ((size_t)(mg * 8 + ks) * 64 + lane) * 8] = v;
}

// biasG rows follow gate row mapping; biasSr plain
__global__ __launch_bounds__(256) void packbias_kernel(
    const float* __restrict__ dsb, const float* __restrict__ asb,
    const float* __restrict__ dtb, const float* __restrict__ atb,
    const float* __restrict__ rsb, const float* __restrict__ skb,
    float* __restrict__ biasG, float* __restrict__ biasSr)
{
    const int idx = blockIdx.x * 256 + threadIdx.x;
    if (idx < 30 * 1024) {
        const int l = idx >> 10, r = idx & 1023;
        const int rsub = r & 63;
        const int c = (r >> 6) * 32 + (rsub & 31);
        const float v = (rsub < 32) ? (dsb[l * 512 + c] + asb[l * 512 + c])
                                    : (dtb[l * 512 + c] + atb[l * 512 + c]);
        biasG[idx] = v;
    } else if (idx < 30 * 1024 + 30 * 768) {
        const int j = idx - 30 * 1024;
        const int l = j / 768, r = j % 768;
        biasSr[j] = (r < 512) ? rsb[l * 512 + r] : skb[l * 256 + (r - 512)];
    }
}

// ---------------------------------------------------------------------------
extern "C" void kernel_launch(void* const* d_in, const int* in_sizes, int n_in,
                              void* d_out, int out_size, void* d_ws, size_t ws_size,
                              hipStream_t stream)
{
    (void)in_sizes; (void)n_in; (void)out_size; (void)ws_size;

    const int* x = (const int*)d_in[0];
    const float* h = (const float*)d_in[1];
    const float* causal_w = (const float*)d_in[2];
    const float* causal_b = (const float*)d_in[3];
    const float* dsw = (const float*)d_in[4];
    const float* dsb = (const float*)d_in[5];
    const float* dtw = (const float*)d_in[6];
    const float* dtb = (const float*)d_in[7];
    const float* asw = (const float*)d_in[8];
    const float* asb = (const float*)d_in[9];
    const float* atw = (const float*)d_in[10];
    const float* atb = (const float*)d_in[11];
    const float* skw = (const float*)d_in[12];
    const float* skb = (const float*)d_in[13];
    const float* rsw = (const float*)d_in[14];
    const float* rsb = (const float*)d_in[15];
    const float* p1w = (const float*)d_in[16];
    const float* p1b = (const float*)d_in[17];
    const float* p2w = (const float*)d_in[18];
    const float* p2b = (const float*)d_in[19];
    const float* lw  = (const float*)d_in[20];
    const float* lb  = (const float*)d_in[21];

    char* ws = (char*)d_ws;
    size_t off = 0;
    auto alloc = [&](size_t bytes) { char* p = ws + off; off += (bytes + 255) & ~(size_t)255; return p; };

    half_t* Wg     = (half_t*)alloc((size_t)L_ * 1114112 * 2);
    half_t* Wsr    = (half_t*)alloc((size_t)L_ * 393216 * 2);
    half_t* Wpost  = (half_t*)alloc((size_t)3 * 65536 * 2);
    float*  biasG  = (float*) alloc((size_t)L_ * 1024 * 4);
    float*  biasSr = (float*) alloc((size_t)L_ * 768 * 4);
    half_t* actB   = (half_t*)alloc((size_t)B_ * T_ * 576 * 2);
    half_t* g      = (half_t*)alloc((size_t)B_ * T_ * 512 * 2);
    half_t* skipH  = (half_t*)alloc((size_t)B_ * T_ * 256 * 2);
    half_t* zbuf   = (half_t*)alloc(256);
    half_t* pA     = (half_t*)alloc((size_t)B_ * T_ * 256 * 2);
    half_t* pB     = (half_t*)alloc((size_t)B_ * T_ * 256 * 2);

    // zero skipH + zbuf (adjacent)
    hipMemsetAsync(skipH, 0, (size_t)B_ * T_ * 256 * 2 + 256, stream);

    packgate_kernel<<<30 * 64 * 16 * 64 / 256, 256, 0, stream>>>(dsw, dtw, Wg);
    packgaux_kernel<<<30 * 64 * 2 * 64 / 256, 256, 0, stream>>>(asw, atw, Wg);
    packsr_kernel<<<30 * 48 * 16 * 64 / 256, 256, 0, stream>>>(rsw, skw, Wsr);
    packpost_kernel<<<3 * 16 * 8 * 64 / 256, 256, 0, stream>>>(p1w, p2w, lw, Wpost);
    packbias_kernel<<<(30 * 1024 + 30 * 768 + 255) / 256, 256, 0, stream>>>(
        dsb, asb, dtb, atb, rsb, skb, biasG, biasSr);
    packh_kernel<<<B_ * T_ * 64 / 256, 256, 0, stream>>>(h, actB);
    embed_kernel<<<dim3(T_, B_), 256, 0, stream>>>(x, causal_w, causal_b, actB);

    for (int l = 0; l < L_; l++) {
        const int dil = 1 << (l % 10);
        gates_gemm<<<dim3(32, 8, B_), 256, 0, stream>>>(
            actB, Wg + (size_t)l * 1114112, biasG + (size_t)l * 1024, g, zbuf, dil);
        gemm_mfma<512, 3><<<dim3(32, 6, B_), 256, 0, stream>>>(
            g, Wsr + (size_t)l * 393216, biasSr + (size_t)l * 768, nullptr, 768,
            actB, skipH);
    }

    relupack_kernel<<<B_ * T_ * 64 / 256, 256, 0, stream>>>(skipH, pA);
    gemm_mfma<256, 1><<<dim3(32, 2, B_), 256, 0, stream>>>(pA, Wpost, p1b, pB, 256,
                                                           nullptr, nullptr);
    gemm_mfma<256, 0><<<dim3(32, 2, B_), 256, 0, stream>>>(pB, Wpost + 65536, p2b, pA, 256,
                                                           nullptr, nullptr);
    gemm_mfma<256, 2><<<dim3(32, 2, B_), 256, 0, stream>>>(pA, Wpost + 131072, lb, d_out, 256,
                                                           nullptr, nullptr);
}

// Round 2
// 1474.998 us; speedup vs baseline: 1.0405x; 1.0281x over previous
//
#include <hip/hip_runtime.h>
#include <cstddef>

#define B_ 2
#define T_ 4096
#define NQ_ 256
#define NAUX_ 28
#define NR_ 512
#define NS_ 256
#define L_ 30

typedef _Float16 half_t;
typedef __attribute__((ext_vector_type(8))) _Float16 f16x8;
typedef __attribute__((ext_vector_type(4))) _Float16 f16x4;
typedef __attribute__((ext_vector_type(4))) float f32x4;

__device__ inline half_t f2h(float f) { return (half_t)f; }
__device__ inline float h2f(half_t h) { return (float)h; }

// async global->LDS, 16 B per lane; LDS dest = wave base + lane*16
__device__ __forceinline__ void gload16(const void* g, void* l) {
    __builtin_amdgcn_global_load_lds(
        (const __attribute__((address_space(1))) unsigned int*)g,
        (__attribute__((address_space(3))) unsigned int*)l, 16, 0, 0);
}

// phase barrier: raw s_barrier (NO vmcnt(0) drain), compiler memory fence
__device__ __forceinline__ void phase_barrier() {
    asm volatile("" ::: "memory");
    __builtin_amdgcn_s_barrier();
    asm volatile("" ::: "memory");
}
// tile gate: counted vmcnt (6 = one staged tile in flight: 2 A + 4 B loads)
__device__ __forceinline__ void gate_barrier() {
    asm volatile("s_waitcnt vmcnt(6)" ::: "memory");
    __builtin_amdgcn_s_barrier();
    asm volatile("" ::: "memory");
}

// ---------------------------------------------------------------------------
// Weight fragment-blob layout: for M x K weights, blob(mg, ks) holds the
// 16-row x 32-col MFMA A-fragment for m in [mg*16,mg*16+16), k in [ks*32,+32):
// 64 lanes x 8 halves contiguous; lane l -> row mg*16+(l&15), k ks*32+(l>>4)*8.
// Flat half offset: (mg*NKS + ks)*512 + lane*8, NKS = K/32.
// ---------------------------------------------------------------------------

// ---------------------------------------------------------------------------
// gates8: fused gates GEMM + gating, counted-vmcnt phase schedule.
// BM=128 (m), BN=256 (t), BK=64. 512 thr = 8 waves (2m x 4n), wave out 64x64.
// LDS triple-buffered: buf[t%3] read while buf[(t+2)%3] is staged (that buf
// was last read at tile t-1, >=2 barriers earlier -> race-free).
// Per K-tile: ph1 {read A frags + B(s=0) frags, issue A-stage(t+2), barrier,
// 16 MFMA}, ph2 {read B(s=1), issue B-stage(t+2), vmcnt(6)+barrier, 16 MFMA}.
// K-tiles v: [0,8)=cur slice v, [8,16)=past(t-dil), 16=aux. grid (16,8,B).
// ---------------------------------------------------------------------------
__global__ __launch_bounds__(512, 2) void gates8(
    const half_t* __restrict__ actB, const half_t* __restrict__ Wf,
    const float* __restrict__ biasG, half_t* __restrict__ g,
    const half_t* __restrict__ zbuf, int dil)
{
    __shared__ __align__(16) half_t sA[3][16 * 512];   // 48 KB: 16 frag slots/buf
    __shared__ __align__(16) half_t sB[3][256 * 64];   // 96 KB

    const int tid = threadIdx.x;
    const int b = blockIdx.z;
    const int tB = blockIdx.x * 256;
    const int w = tid >> 6, lane = tid & 63;
    const int wm = w >> 2, wn = w & 3;
    const int l15 = lane & 15, lg = lane >> 4;
    const int rr = lane >> 3, cc = lane & 7;
    const int sc8 = cc ^ rr;
    const int mgB = blockIdx.y * 8;            // block m-groups [mgB, mgB+8)

    f32x4 acc[4][4] = {};
    f16x8 af[4][2];

    // wave w stages A fragments for mg = mgB + w, ks in {0,1} of tile v
    auto stageA = [&](int v, int buf) {
#pragma unroll
        for (int s2 = 0; s2 < 2; s2++)
            gload16(&Wf[((size_t)(mgB + w) * 34 + v * 2 + s2) * 512 + lane * 8],
                    &sA[buf][(w * 2 + s2) * 512]);
    };
    auto stageB = [&](int v, int buf) {
#pragma unroll
        for (int it = 0; it < 4; it++) {
            const int t = tB + w * 32 + it * 8 + rr;
            const half_t* p;
            if (v < 8) {
                p = actB + ((size_t)b * T_ + t) * 576 + v * 64;
            } else if (v < 16) {
                const int tp = t - dil;
                p = (tp >= 0) ? actB + ((size_t)b * T_ + tp) * 576 + (v - 8) * 64
                              : zbuf;
            } else {
                p = actB + ((size_t)b * T_ + t) * 576 + 512;
            }
            gload16(p + sc8 * 8, &sB[buf][(w * 32 + it * 8) * 64]);
        }
    };
    auto loadAfrag = [&](int buf) {
#pragma unroll
        for (int i = 0; i < 4; i++)
#pragma unroll
            for (int s = 0; s < 2; s++)
                af[i][s] = *(const f16x8*)&sA[buf][((wm * 4 + i) * 2 + s) * 512 + lane * 8];
    };
    auto loadBfrag = [&](f16x8* bv, int s, int buf) {
#pragma unroll
        for (int j = 0; j < 4; j++) {
            const int r = wn * 64 + j * 16 + l15;
            bv[j] = *(const f16x8*)&sB[buf][r * 64 + (((s * 4 + lg) ^ (l15 & 7)) * 8)];
        }
    };
    auto mfma16 = [&](const f16x8* bv, int s) {
        __builtin_amdgcn_s_setprio(1);
#pragma unroll
        for (int i = 0; i < 4; i++)
#pragma unroll
            for (int j = 0; j < 4; j++)
                acc[i][j] = __builtin_amdgcn_mfma_f32_16x16x32_f16(af[i][s], bv[j], acc[i][j], 0, 0, 0);
        __builtin_amdgcn_s_setprio(0);
    };

    // prologue: stage tiles 0,1; gate tile0 (vmcnt(6) leaves tile1's 6 in flight)
    stageA(0, 0); stageB(0, 0);
    stageA(1, 1); stageB(1, 1);
    asm volatile("s_waitcnt vmcnt(6)" ::: "memory");
    __builtin_amdgcn_s_barrier();
    asm volatile("" ::: "memory");

    int buf = 0, nbuf = 2;
    for (int t = 0; t < 17; t++) {
        // ph1
        loadAfrag(buf);
        f16x8 bv0[4];
        loadBfrag(bv0, 0, buf);
        if (t + 2 < 17) stageA(t + 2, nbuf);
        phase_barrier();
        mfma16(bv0, 0);
        // ph2
        f16x8 bv1[4];
        loadBfrag(bv1, 1, buf);
        if (t + 2 < 17) stageB(t + 2, nbuf);
        gate_barrier();                 // tile t+1 now fully resident
        mfma16(bv1, 1);
        buf = (buf == 2) ? 0 : buf + 1;
        nbuf = (nbuf == 2) ? 0 : nbuf + 1;
    }

    // epilogue: gating (identical mapping to verified round-1 kernel)
    const int gidx = blockIdx.y * 2 + wm;
    const int t0 = tB + wn * 64 + l15;
#pragma unroll
    for (int i = 0; i < 2; i++) {
        const int c = gidx * 32 + i * 16 + lg * 4;
        const float4 bs = *(const float4*)&biasG[gidx * 64 + i * 16 + lg * 4];
        const float4 bt4 = *(const float4*)&biasG[gidx * 64 + 32 + i * 16 + lg * 4];
        const float bsa[4] = {bs.x, bs.y, bs.z, bs.w};
        const float bta[4] = {bt4.x, bt4.y, bt4.z, bt4.w};
#pragma unroll
        for (int j = 0; j < 4; j++) {
            const int t = t0 + j * 16;
            f16x4 o;
#pragma unroll
            for (int e = 0; e < 4; e++) {
                const float sv = acc[i][j][e] + bsa[e];
                const float tv = acc[i + 2][j][e] + bta[e];
                const float sg = 1.f / (1.f + __expf(-sv));
                const float ex = __expf(-2.f * tv);
                const float th = (1.f - ex) / (1.f + ex);
                o[e] = f2h(sg * th);
            }
            *(f16x4*)(g + ((size_t)b * T_ + t) * 512 + c) = o;
        }
    }
}

// ---------------------------------------------------------------------------
// res8: res/skip GEMM (M=768, K=512), same counted-vmcnt schedule as gates8.
// Fused fp16 RMW epilogue: m<512 -> actB residual, m>=512 -> skipH.
// grid (16, 6, B), 512 threads.
// ---------------------------------------------------------------------------
__global__ __launch_bounds__(512, 2) void res8(
    const half_t* __restrict__ X, const half_t* __restrict__ Wf,
    const float* __restrict__ bias, half_t* __restrict__ actB,
    half_t* __restrict__ skipH)
{
    __shared__ __align__(16) half_t sA[3][16 * 512];
    __shared__ __align__(16) half_t sB[3][256 * 64];

    const int tid = threadIdx.x;
    const int b = blockIdx.z;
    const int tB = blockIdx.x * 256;
    const int mB = blockIdx.y * 128;
    const int w = tid >> 6, lane = tid & 63;
    const int wm = w >> 2, wn = w & 3;
    const int l15 = lane & 15, lg = lane >> 4;
    const int rr = lane >> 3, cc = lane & 7;
    const int sc8 = cc ^ rr;
    const int mgB = blockIdx.y * 8;

    f32x4 acc[4][4] = {};
    f16x8 af[4][2];

    const half_t* Xb = X + ((size_t)b * T_ + tB) * 512;

    auto stageA = [&](int v, int buf) {
#pragma unroll
        for (int s2 = 0; s2 < 2; s2++)
            gload16(&Wf[((size_t)(mgB + w) * 16 + v * 2 + s2) * 512 + lane * 8],
                    &sA[buf][(w * 2 + s2) * 512]);
    };
    auto stageB = [&](int v, int buf) {
#pragma unroll
        for (int it = 0; it < 4; it++) {
            const int row = w * 32 + it * 8;
            gload16(Xb + (size_t)(row + rr) * 512 + v * 64 + sc8 * 8,
                    &sB[buf][row * 64]);
        }
    };
    auto loadAfrag = [&](int buf) {
#pragma unroll
        for (int i = 0; i < 4; i++)
#pragma unroll
            for (int s = 0; s < 2; s++)
                af[i][s] = *(const f16x8*)&sA[buf][((wm * 4 + i) * 2 + s) * 512 + lane * 8];
    };
    auto loadBfrag = [&](f16x8* bv, int s, int buf) {
#pragma unroll
        for (int j = 0; j < 4; j++) {
            const int r = wn * 64 + j * 16 + l15;
            bv[j] = *(const f16x8*)&sB[buf][r * 64 + (((s * 4 + lg) ^ (l15 & 7)) * 8)];
        }
    };
    auto mfma16 = [&](const f16x8* bv, int s) {
        __builtin_amdgcn_s_setprio(1);
#pragma unroll
        for (int i = 0; i < 4; i++)
#pragma unroll
            for (int j = 0; j < 4; j++)
                acc[i][j] = __builtin_amdgcn_mfma_f32_16x16x32_f16(af[i][s], bv[j], acc[i][j], 0, 0, 0);
        __builtin_amdgcn_s_setprio(0);
    };

    stageA(0, 0); stageB(0, 0);
    stageA(1, 1); stageB(1, 1);
    asm volatile("s_waitcnt vmcnt(6)" ::: "memory");
    __builtin_amdgcn_s_barrier();
    asm volatile("" ::: "memory");

    int buf = 0, nbuf = 2;
    for (int t = 0; t < 8; t++) {
        loadAfrag(buf);
        f16x8 bv0[4];
        loadBfrag(bv0, 0, buf);
        if (t + 2 < 8) stageA(t + 2, nbuf);
        phase_barrier();
        mfma16(bv0, 0);
        f16x8 bv1[4];
        loadBfrag(bv1, 1, buf);
        if (t + 2 < 8) stageB(t + 2, nbuf);
        gate_barrier();
        mfma16(bv1, 1);
        buf = (buf == 2) ? 0 : buf + 1;
        nbuf = (nbuf == 2) ? 0 : nbuf + 1;
    }

    const int n0 = tB + wn * 64 + l15;
#pragma unroll
    for (int i = 0; i < 4; i++) {
        const int m = mB + wm * 64 + i * 16 + lg * 4;
        const float4 bv = *(const float4*)&bias[m];
#pragma unroll
        for (int j = 0; j < 4; j++) {
            const int t = n0 + j * 16;
            const float o0 = acc[i][j][0] + bv.x, o1 = acc[i][j][1] + bv.y;
            const float o2 = acc[i][j][2] + bv.z, o3 = acc[i][j][3] + bv.w;
            const size_t bt = (size_t)b * T_ + t;
            half_t* p = (mB + wm * 64 + i * 16 < 512)
                            ? (actB + bt * 576 + m)
                            : (skipH + bt * 256 + (m - 512));
            f16x4 old = *(const f16x4*)p;
            f16x4 nv = {f2h(h2f(old.x) + o0), f2h(h2f(old.y) + o1),
                        f2h(h2f(old.z) + o2), f2h(h2f(old.w) + o3)};
            *(f16x4*)p = nv;
        }
    }
}

// ---------------------------------------------------------------------------
// Generic GEMM (old 2-phase template) — retained for the small post GEMMs.
// K compile-time (256). EPI: 0 fp16, 1 fp16+relu, 2 f32.
// ---------------------------------------------------------------------------
template<int K, int EPI>
__global__ __launch_bounds__(256, 2) void gemm_mfma(
    const half_t* __restrict__ X, const half_t* __restrict__ Wf,
    const float* __restrict__ bias, void* __restrict__ out, int M,
    half_t* __restrict__ actB, half_t* __restrict__ skipH)
{
    constexpr int NITER = K / 128;
    constexpr int NKS = K / 32;
    __shared__ __align__(16) half_t sB[2][256 * 64];

    const int tid = threadIdx.x;
    const int b = blockIdx.z;
    const int tB = blockIdx.x * 128;
    const int mB = blockIdx.y * 128;
    const int w = tid >> 6, lane = tid & 63;
    const int wm = w >> 1, wn = w & 1;
    const int l15 = lane & 15, lg = lane >> 4;
    const int rr = lane >> 3, cc = lane & 7;
    const int sc8 = cc ^ rr;

    f32x4 acc[4][4] = {};
    f16x8 aC[8], aP[8];

    const int mgW = (mB >> 4) + wm * 4;
    const half_t* Xb = X + ((size_t)b * T_ + tB) * K;

    auto loadA = [&](f16x8* d, int v) {
#pragma unroll
        for (int i = 0; i < 4; i++)
#pragma unroll
            for (int s = 0; s < 2; s++)
                d[i * 2 + s] = *(const f16x8*)&Wf[((size_t)(mgW + i) * NKS + v * 2 + s) * 512 + lane * 8];
    };
    auto stageSlice = [&](int v, int rowbase, int buf) {
#pragma unroll
        for (int it = 0; it < 4; it++) {
            const int row = w * 32 + it * 8;
            gload16(Xb + (size_t)(row + rr) * K + v * 64 + sc8 * 8,
                    &sB[buf][(rowbase + row) * 64]);
        }
    };
    auto compute = [&](const f16x8* a, int rowbase, int buf) {
#pragma unroll
        for (int s = 0; s < 2; s++) {
            f16x8 bv[4];
#pragma unroll
            for (int j = 0; j < 4; j++) {
                const int r = rowbase + wn * 64 + j * 16 + l15;
                bv[j] = *(const f16x8*)&sB[buf][r * 64 + (((s * 4 + lg) ^ (l15 & 7)) * 8)];
            }
#pragma unroll
            for (int i = 0; i < 4; i++)
#pragma unroll
                for (int j = 0; j < 4; j++)
                    acc[i][j] = __builtin_amdgcn_mfma_f32_16x16x32_f16(a[i * 2 + s], bv[j], acc[i][j], 0, 0, 0);
        }
    };

    stageSlice(0, 0, 0);
    stageSlice(1, 128, 0);
    loadA(aC, 0);
    loadA(aP, 1);
#pragma unroll
    for (int kc = 0; kc < NITER; kc++) {
        __syncthreads();
        if (kc + 1 < NITER) {
            stageSlice(2 * kc + 2, 0, (kc + 1) & 1);
            stageSlice(2 * kc + 3, 128, (kc + 1) & 1);
        }
        compute(aC, 0, kc & 1);
        if (kc + 1 < NITER) loadA(aC, 2 * kc + 2);
        compute(aP, 128, kc & 1);
        if (kc + 1 < NITER) loadA(aP, 2 * kc + 3);
    }

    const int n0 = tB + wn * 64 + l15;
#pragma unroll
    for (int i = 0; i < 4; i++) {
        const int m = mB + wm * 64 + i * 16 + lg * 4;
        float4 bv = make_float4(0.f, 0.f, 0.f, 0.f);
        if (bias) bv = *(const float4*)&bias[m];
#pragma unroll
        for (int j = 0; j < 4; j++) {
            const int t = n0 + j * 16;
            float o0 = acc[i][j][0] + bv.x, o1 = acc[i][j][1] + bv.y;
            float o2 = acc[i][j][2] + bv.z, o3 = acc[i][j][3] + bv.w;
            if (EPI == 1) {
                o0 = fmaxf(o0, 0.f); o1 = fmaxf(o1, 0.f);
                o2 = fmaxf(o2, 0.f); o3 = fmaxf(o3, 0.f);
            }
            if (EPI == 3) {
                const size_t bt = (size_t)b * T_ + t;
                half_t* p = (mB < 512) ? (actB + bt * 576 + m)
                                       : (skipH + bt * 256 + (m - 512));
                f16x4 old = *(const f16x4*)p;
                f16x4 nv = {f2h(h2f(old.x) + o0), f2h(h2f(old.y) + o1),
                            f2h(h2f(old.z) + o2), f2h(h2f(old.w) + o3)};
                *(f16x4*)p = nv;
            } else {
                const size_t off = ((size_t)b * T_ + t) * M + m;
                if (EPI == 2) {
                    *(float4*)((float*)out + off) = make_float4(o0, o1, o2, o3);
                } else {
                    f16x4 ov = {f2h(o0), f2h(o1), f2h(o2), f2h(o3)};
                    *(f16x4*)((half_t*)out + off) = ov;
                }
            }
        }
    }
}

// relu(skipH) -> fp16 dense
__global__ __launch_bounds__(256) void relupack_kernel(
    const half_t* __restrict__ skipH, half_t* __restrict__ outp)
{
    const int idx = blockIdx.x * 256 + threadIdx.x;     // 8192*64
    const int c = (idx & 63) * 4;
    const int bt = idx >> 6;
    const f16x4 v = *(const f16x4*)(skipH + (size_t)bt * 256 + c);
    f16x4 o = {f2h(fmaxf(h2f(v.x), 0.f)), f2h(fmaxf(h2f(v.y), 0.f)),
               f2h(fmaxf(h2f(v.z), 0.f)), f2h(fmaxf(h2f(v.w), 0.f))};
    *(f16x4*)(outp + (size_t)bt * 256 + c) = o;
}

// ---------------------------------------------------------------------------
// Embed: actB[t][c] = fp16(cw[c][x[t]][1] + cw[c][x[t-1]][0] + cb[c])
// ---------------------------------------------------------------------------
__global__ __launch_bounds__(256) void embed_kernel(
    const int* __restrict__ x, const float* __restrict__ cw,
    const float* __restrict__ cb, half_t* __restrict__ actB)
{
    const int t = blockIdx.x, b = blockIdx.y;
    const int idc = x[b * T_ + t];
    const int idp = (t > 0) ? x[b * T_ + t - 1] : -1;
    const size_t bt = (size_t)b * T_ + t;
    for (int c = threadIdx.x; c < 512; c += 256) {
        float v = cw[(c * 256 + idc) * 2 + 1] + cb[c];
        if (idp >= 0) v += cw[(c * 256 + idp) * 2 + 0];
        actB[bt * 576 + c] = f2h(v);
    }
}

// aux channels: actB[t][512+j] = fp16(h[b][j][t]) for j<28 else 0
__global__ __launch_bounds__(256) void packh_kernel(
    const float* __restrict__ h, half_t* __restrict__ actB)
{
    const int idx = blockIdx.x * 256 + threadIdx.x;     // 8192*64
    const int j = idx & 63;
    const int bt = idx >> 6;
    const int b = bt >> 12, t = bt & 4095;
    const float v = (j < 28) ? h[((size_t)b * NAUX_ + j) * T_ + t] : 0.f;
    actB[(size_t)bt * 576 + 512 + j] = f2h(v);
}

// ---------------------------------------------------------------------------
// Pack gate weights into blob layout. Wg per layer = 64 mg x 34 ks x 512 h.
// ---------------------------------------------------------------------------
__global__ __launch_bounds__(256) void packgate_kernel(
    const float* __restrict__ dsw, const float* __restrict__ dtw,
    half_t* __restrict__ Wg)
{
    const int idx = blockIdx.x * 256 + threadIdx.x;     // 30*64*16*64
    const int lane = idx & 63;
    const int ks = (idx >> 6) & 15;
    const int mg = (idx >> 10) & 63;
    const int l = idx >> 16;
    const int r = mg * 16 + (lane & 15);
    const int rsub = r & 63;
    const int c = (r >> 6) * 32 + (rsub & 31);
    const float* src = (rsub < 32) ? dsw : dtw;
    const size_t base = ((size_t)(l * 512 + c) * 512 + ks * 32 + (lane >> 4) * 8) * 2;
    const float4* p = (const float4*)(src + base);
    const float4 q0 = p[0], q1 = p[1], q2 = p[2], q3 = p[3];
    f16x8 cur = {f2h(q0.y), f2h(q0.w), f2h(q1.y), f2h(q1.w),
                 f2h(q2.y), f2h(q2.w), f2h(q3.y), f2h(q3.w)};
    f16x8 pst = {f2h(q0.x), f2h(q0.z), f2h(q1.x), f2h(q1.z),
                 f2h(q2.x), f2h(q2.z), f2h(q3.x), f2h(q3.z)};
    half_t* dst = Wg + (size_t)l * 1114112;
    *(f16x8*)&dst[((size_t)(mg * 34 + ks) * 64 + lane) * 8] = cur;
    *(f16x8*)&dst[((size_t)(mg * 34 + 16 + ks) * 64 + lane) * 8] = pst;
}

// aux blob slots ks=32,33 of Wg
__global__ __launch_bounds__(256) void packgaux_kernel(
    const float* __restrict__ asw, const float* __restrict__ atw,
    half_t* __restrict__ Wg)
{
    const int idx = blockIdx.x * 256 + threadIdx.x;     // 30*64*2*64
    const int lane = idx & 63;
    const int ksd = (idx >> 6) & 1;
    const int mg = (idx >> 7) & 63;
    const int l = idx >> 13;
    const int r = mg * 16 + (lane & 15);
    const int rsub = r & 63;
    const int c = (r >> 6) * 32 + (rsub & 31);
    const float* src = (rsub < 32) ? asw : atw;
    const int j0 = ksd * 32 + (lane >> 4) * 8;
    f16x8 v = {};
#pragma unroll
    for (int e = 0; e < 8; e++) {
        const int j = j0 + e;
        if (j < NAUX_) v[e] = f2h(src[(size_t)(l * 512 + c) * NAUX_ + j]);
    }
    Wg += (size_t)l * 1114112;
    *(f16x8*)&Wg[((size_t)(mg * 34 + 32 + ksd) * 64 + lane) * 8] = v;
}

// sr weights blob: 48 mg x 16 ks x 512 h per layer
__global__ __launch_bounds__(256) void packsr_kernel(
    const float* __restrict__ rsw, const float* __restrict__ skw,
    half_t* __restrict__ Wsr)
{
    const int idx = blockIdx.x * 256 + threadIdx.x;     // 30*48*16*64
    const int lane = idx & 63;
    const int ks = (idx >> 6) & 15;
    const int mg = (idx >> 10) % 48;
    const int l = (idx >> 10) / 48;
    const int r = mg * 16 + (lane & 15);
    const int kb = ks * 32 + (lane >> 4) * 8;
    const float* src = (r < 512) ? (rsw + ((size_t)l * 512 + r) * 512 + kb)
                                 : (skw + ((size_t)l * 256 + (r - 512)) * 512 + kb);
    const float4 q0 = ((const float4*)src)[0], q1 = ((const float4*)src)[1];
    f16x8 v = {f2h(q0.x), f2h(q0.y), f2h(q0.z), f2h(q0.w),
               f2h(q1.x), f2h(q1.y), f2h(q1.z), f2h(q1.w)};
    *(f16x8*)&Wsr[(size_t)l * 393216 + ((size_t)(mg * 16 + ks) * 64 + lane) * 8] = v;
}

// post weights blob: 16 mg x 8 ks x 512 h per matrix
__global__ __launch_bounds__(256) void packpost_kernel(
    const float* __restrict__ p1w, const float* __restrict__ p2w,
    const float* __restrict__ lw, half_t* __restrict__ Wpost)
{
    const int idx = blockIdx.x * 256 + threadIdx.x;     // 3*16*8*64
    const int lane = idx & 63;
    const int ks = (idx >> 6) & 7;
    const int mg = (idx >> 9) & 15;
    const int mi = idx >> 13;
    const float* src = (mi == 0) ? p1w : (mi == 1) ? p2w : lw;
    const int r = mg * 16 + (lane & 15);
    const int kb = ks * 32 + (lane >> 4) * 8;
    const float4 q0 = ((const float4*)(src + (size_t)r * 256 + kb))[0];
    const float4 q1 = ((const float4*)(src + (size_t)r * 256 + kb))[1];
    f16x8 v = {f2h(q0.x), f2h(q0.y), f2h(q0.z), f2h(q0.w),
               f2h(q1.x), f2h(q1.y), f2h(q1.z), f2h(q1.w)};
    *(f16x8*)&Wpost[(size_t)mi * 65536 + ((size_t)(mg * 8 + ks) * 64 + lane) * 8] = v;
}

// biasG rows follow gate row mapping; biasSr plain
__global__ __launch_bounds__(256) void packbias_kernel(
    const float* __restrict__ dsb, const float* __restrict__ asb,
    const float* __restrict__ dtb, const float* __restrict__ atb,
    const float* __restrict__ rsb, const float* __restrict__ skb,
    float* __restrict__ biasG, float* __restrict__ biasSr)
{
    const int idx = blockIdx.x * 256 + threadIdx.x;
    if (idx < 30 * 1024) {
        const int l = idx >> 10, r = idx & 1023;
        const int rsub = r & 63;
        const int c = (r >> 6) * 32 + (rsub & 31);
        const float v = (rsub < 32) ? (dsb[l * 512 + c] + asb[l * 512 + c])
                                    : (dtb[l * 512 + c] + atb[l * 512 + c]);
        biasG[idx] = v;
    } else if (idx < 30 * 1024 + 30 * 768) {
        const int j = idx - 30 * 1024;
        const int l = j / 768, r = j % 768;
        biasSr[j] = (r < 512) ? rsb[l * 512 + r] : skb[l * 256 + (r - 512)];
    }
}

// ---------------------------------------------------------------------------
extern "C" void kernel_launch(void* const* d_in, const int* in_sizes, int n_in,
                              void* d_out, int out_size, void* d_ws, size_t ws_size,
                              hipStream_t stream)
{
    (void)in_sizes; (void)n_in; (void)out_size; (void)ws_size;

    const int* x = (const int*)d_in[0];
    const float* h = (const float*)d_in[1];
    const float* causal_w = (const float*)d_in[2];
    const float* causal_b = (const float*)d_in[3];
    const float* dsw = (const float*)d_in[4];
    const float* dsb = (const float*)d_in[5];
    const float* dtw = (const float*)d_in[6];
    const float* dtb = (const float*)d_in[7];
    const float* asw = (const float*)d_in[8];
    const float* asb = (const float*)d_in[9];
    const float* atw = (const float*)d_in[10];
    const float* atb = (const float*)d_in[11];
    const float* skw = (const float*)d_in[12];
    const float* skb = (const float*)d_in[13];
    const float* rsw = (const float*)d_in[14];
    const float* rsb = (const float*)d_in[15];
    const float* p1w = (const float*)d_in[16];
    const float* p1b = (const float*)d_in[17];
    const float* p2w = (const float*)d_in[18];
    const float* p2b = (const float*)d_in[19];
    const float* lw  = (const float*)d_in[20];
    const float* lb  = (const float*)d_in[21];

    char* ws = (char*)d_ws;
    size_t off = 0;
    auto alloc = [&](size_t bytes) { char* p = ws + off; off += (bytes + 255) & ~(size_t)255; return p; };

    half_t* Wg     = (half_t*)alloc((size_t)L_ * 1114112 * 2);
    half_t* Wsr    = (half_t*)alloc((size_t)L_ * 393216 * 2);
    half_t* Wpost  = (half_t*)alloc((size_t)3 * 65536 * 2);
    float*  biasG  = (float*) alloc((size_t)L_ * 1024 * 4);
    float*  biasSr = (float*) alloc((size_t)L_ * 768 * 4);
    half_t* actB   = (half_t*)alloc((size_t)B_ * T_ * 576 * 2);
    half_t* g      = (half_t*)alloc((size_t)B_ * T_ * 512 * 2);
    half_t* skipH  = (half_t*)alloc((size_t)B_ * T_ * 256 * 2);
    half_t* zbuf   = (half_t*)alloc(256);
    half_t* pA     = (half_t*)alloc((size_t)B_ * T_ * 256 * 2);
    half_t* pB     = (half_t*)alloc((size_t)B_ * T_ * 256 * 2);

    // zero skipH + zbuf (adjacent)
    hipMemsetAsync(skipH, 0, (size_t)B_ * T_ * 256 * 2 + 256, stream);

    packgate_kernel<<<30 * 64 * 16 * 64 / 256, 256, 0, stream>>>(dsw, dtw, Wg);
    packgaux_kernel<<<30 * 64 * 2 * 64 / 256, 256, 0, stream>>>(asw, atw, Wg);
    packsr_kernel<<<30 * 48 * 16 * 64 / 256, 256, 0, stream>>>(rsw, skw, Wsr);
    packpost_kernel<<<3 * 16 * 8 * 64 / 256, 256, 0, stream>>>(p1w, p2w, lw, Wpost);
    packbias_kernel<<<(30 * 1024 + 30 * 768 + 255) / 256, 256, 0, stream>>>(
        dsb, asb, dtb, atb, rsb, skb, biasG, biasSr);
    packh_kernel<<<B_ * T_ * 64 / 256, 256, 0, stream>>>(h, actB);
    embed_kernel<<<dim3(T_, B_), 256, 0, stream>>>(x, causal_w, causal_b, actB);

    for (int l = 0; l < L_; l++) {
        const int dil = 1 << (l % 10);
        gates8<<<dim3(16, 8, B_), 512, 0, stream>>>(
            actB, Wg + (size_t)l * 1114112, biasG + (size_t)l * 1024, g, zbuf, dil);
        res8<<<dim3(16, 6, B_), 512, 0, stream>>>(
            g, Wsr + (size_t)l * 393216, biasSr + (size_t)l * 768, actB, skipH);
    }

    relupack_kernel<<<B_ * T_ * 64 / 256, 256, 0, stream>>>(skipH, pA);
    gemm_mfma<256, 1><<<dim3(32, 2, B_), 256, 0, stream>>>(pA, Wpost, p1b, pB, 256,
                                                           nullptr, nullptr);
    gemm_mfma<256, 0><<<dim3(32, 2, B_), 256, 0, stream>>>(pB, Wpost + 65536, p2b, pA, 256,
                                                           nullptr, nullptr);
    gemm_mfma<256, 2><<<dim3(32, 2, B_), 256, 0, stream>>>(pA, Wpost + 131072, lb, d_out, 256,
                                                           nullptr, nullptr);
}